// Round 11
// baseline (213.430 us; speedup 1.0000x reference)
//
#include <hip/hip_runtime.h>
#include <hip/hip_bf16.h>
#include <math.h>

#define B_   8
#define CIN  32
#define COUT 64
#define KK_  4
#define DD   32
#define HH   64
#define WW   64
#define HW   (HH*WW)        // 4096
#define DHW  (DD*HH*WW)     // 131072

typedef __attribute__((ext_vector_type(8)))  short bf16x8;
typedef __attribute__((ext_vector_type(16))) float f32x16;

__device__ __forceinline__ unsigned short f2bf(float f) {
    union { float f; unsigned int u; } v; v.f = f;
    return (unsigned short)((v.u + 0x7FFFu + ((v.u >> 16) & 1u)) >> 16);   // RNE
}
__device__ __forceinline__ void gll16(const void* g, void* l) {
    __builtin_amdgcn_global_load_lds(
        (const __attribute__((address_space(1))) void*)g,
        (__attribute__((address_space(3))) void*)l, 16, 0, 0);
}

// ---------------- 1) transpose x -> bf16 xt rows + fused pooling partials ------
__global__ __launch_bounds__(256) void transpose_kernel(const float* __restrict__ x,
                                                        unsigned short* __restrict__ xt,
                                                        float* __restrict__ pblk) {
    const int t = threadIdx.x;
    const int r = t >> 6, w = t & 63;
    const int hb = blockIdx.x;
    const int h = (hb << 2) + r;
    const int d = blockIdx.y, b = blockIdx.z;

    const float* xb = x + (size_t)b*CIN*DHW + (size_t)d*HW + (size_t)h*WW + w;
    float f[CIN];
    #pragma unroll
    for (int c = 0; c < CIN; ++c) f[c] = xb[(size_t)c * DHW];

    unsigned int packed[CIN/2];
    #pragma unroll
    for (int c2 = 0; c2 < CIN/2; ++c2) {
        unsigned int lo = f2bf(f[2*c2]);
        unsigned int hi = f2bf(f[2*c2+1]);
        packed[c2] = lo | (hi << 16);
    }
    char* row = (char*)xt + (size_t)((b*DD + d)*HH + h) * 4096;
    #pragma unroll
    for (int q = 0; q < 4; ++q) {
        uint4 v = make_uint4(packed[4*q], packed[4*q+1], packed[4*q+2], packed[4*q+3]);
        *(uint4*)(row + q*1024 + (((w << 4)) ^ (q << 4))) = v;
    }

    #pragma unroll
    for (int off = 32; off > 0; off >>= 1) {
        #pragma unroll
        for (int c = 0; c < CIN; ++c) f[c] += __shfl_xor(f[c], off);
    }
    __shared__ float ws4[4][CIN];
    if ((t & 63) < CIN) ws4[r][t & 63] = f[t & 63];
    __syncthreads();
    if (t < CIN)
        pblk[(size_t)((b*DD + d)*16 + hb)*CIN + t] =
            ws4[0][t] + ws4[1][t] + ws4[2][t] + ws4[3][t];
}

// ---------------- 2) attention MLP + softmax + agg bias ----------------
__device__ __forceinline__ float gelu_erf(float v) {
    return 0.5f * v * (1.f + erff(v * 0.70710678118654752f));
}

__global__ void attn_kernel(const float* __restrict__ pblk,
                            const float* __restrict__ temperature,
                            const float* __restrict__ bn1_g, const float* __restrict__ bn1_b,
                            const float* __restrict__ w1,    const float* __restrict__ b1,
                            const float* __restrict__ bn2_g, const float* __restrict__ bn2_b,
                            const float* __restrict__ w2,    const float* __restrict__ b2,
                            const float* __restrict__ bn3_g, const float* __restrict__ bn3_b,
                            const float* __restrict__ w3,    const float* __restrict__ b3,
                            const float* __restrict__ cbias,
                            float* __restrict__ attn_out, float* __restrict__ aggb_out) {
    __shared__ float A[B_][CIN], A2[B_][CIN];
    __shared__ float L[B_][KK_], ATT[B_][KK_];
    const int t = threadIdx.x;
    const int b = t >> 5, c = t & 31;

    float pv = 0.f;
    for (int i = 0; i < DD*16; ++i) pv += pblk[(size_t)(b*DD*16 + i)*CIN + c];
    pv *= (1.f / (float)DHW);

    A[b][c] = gelu_erf(pv * bn1_g[c] + bn1_b[c]);
    __syncthreads();

    float s = b1[c];
    for (int j = 0; j < CIN; ++j) s += A[b][j] * w1[c*CIN + j];
    A2[b][c] = gelu_erf(s * bn2_g[c] + bn2_b[c]);
    __syncthreads();

    float s2 = b2[c];
    for (int j = 0; j < CIN; ++j) s2 += A2[b][j] * w2[c*CIN + j];
    s2 += pv;
    s2 = s2 * bn3_g[c] + bn3_b[c];
    __syncthreads();
    A[b][c] = s2;
    __syncthreads();

    if (c < KK_) {
        float lv = b3[c];
        for (int j = 0; j < CIN; ++j) lv += A[b][j] * w3[c*CIN + j];
        L[b][c] = lv;
    }
    __syncthreads();

    const float T = temperature[0];
    if (c < KK_) {
        float m = fmaxf(fmaxf(L[b][0], L[b][1]), fmaxf(L[b][2], L[b][3]));
        float e = expf((L[b][c] - m) / T);
        float den = 0.f;
        for (int j = 0; j < KK_; ++j) den += expf((L[b][j] - m) / T);
        float av = e / den;
        ATT[b][c] = av;
        attn_out[b*KK_ + c] = av;
    }
    __syncthreads();

    for (int o = c; o < COUT; o += CIN) {
        float sb = 0.f;
        for (int k = 0; k < KK_; ++k) sb += ATT[b][k] * cbias[k*COUT + o];
        aggb_out[b*COUT + o] = sb;
    }
}

// ---------------- 3) aggregate weights -> bf16 wt[b][kpos][co][ci] ----------------
__global__ void aggw_kernel(const float* __restrict__ weight,   // [K][O][CI][27]
                            const float* __restrict__ attn,     // [B][K]
                            unsigned short* __restrict__ wt) {  // [B][27][O][CI] bf16
    const int idx = blockIdx.x * 256 + threadIdx.x;
    const int ci   = idx & 31;
    const int co   = (idx >> 5) & 63;
    int r          = idx >> 11;
    const int kpos = r % 27;
    const int b    = r / 27;
    float s = 0.f;
    #pragma unroll
    for (int k = 0; k < KK_; ++k)
        s += attn[b*KK_ + k] * weight[((k*COUT + co)*CIN + ci)*27 + kpos];
    wt[idx] = f2bf(s);
}

// ---------------- 4) MFMA conv: high-reuse waves (64co x 32w x 4d) ----------------
// flat grid 4096: id = (dt<<9)|(h<<3)|b  (b=id&7 pins b per XCD).
// block 128 = 2 waves (wv halves of w); each wave: M=64co(cb2), N=32w, R=4 d-rows, 1h.
// Per phase (kh,kw): 12 A-loads (x4 reuse), 12 B ds_reads (x4 reuse), 48 MFMA.
// Operand demand: A 32 B/cyc (L2 ok), B 32 B/cyc (LDS 37%) -> matrix pipe can run.
// LDS: 18 data rows + 1 zero row = 76 KiB -> 2 blocks/CU (4 waves/CU, 1/SIMD;
// VGPR cap 512 gives the scheduler a deep window).
__global__ __launch_bounds__(128, 1) void conv_mfma(const unsigned short* __restrict__ xt,
                                                    const unsigned short* __restrict__ wt,
                                                    const float* __restrict__ aggb,
                                                    float* __restrict__ out) {
    __shared__ char smem[19 * 4096];
    const int t    = threadIdx.x;
    const int lane = t & 63;
    const int wv   = t >> 6;            // 0..1 w-half
    const int lw   = lane & 31, lh = lane >> 5;

    const int id = blockIdx.x;
    const int b  = id & 7;              // XCD-pinned
    const int h  = (id >> 3) & 63;
    const int d0 = ((id >> 9) & 7) << 2;

    const char* xb  = (const char*)xt + (size_t)(b*DD)*HH*4096;
    const char* wtb = (const char*)wt + (size_t)b * 27 * 4096;

    // zero row (idx 18): 128 threads x 2 x 16B
    *(uint4*)&smem[18*4096 + t*32]      = make_uint4(0u,0u,0u,0u);
    *(uint4*)&smem[18*4096 + t*32 + 16] = make_uint4(0u,0u,0u,0u);

    // stage 18 data rows (slab j 0..5 x ho 0..2), split across the 2 waves
    for (int rid = wv; rid < 18; rid += 2) {
        const int j = rid / 3, ho = rid % 3;
        const int zd = d0 - 1 + j, yh = h - 1 + ho;
        char* dst = smem + (size_t)(rid << 12);
        if ((unsigned)zd < DD && (unsigned)yh < HH) {
            const char* src = xb + (size_t)(zd*HH + yh)*4096 + lane*16;
            #pragma unroll
            for (int q = 0; q < 4; ++q) gll16(src + (q << 10), dst + (q << 10));
        } else {
            #pragma unroll
            for (int q = 0; q < 4; ++q)
                *(uint4*)(dst + (q << 10) + lane*16) = make_uint4(0u,0u,0u,0u);
        }
    }
    __syncthreads();

    f32x16 acc[2][4];                   // [cb][r]
    #pragma unroll
    for (int cb = 0; cb < 2; ++cb)
        #pragma unroll
        for (int r = 0; r < 4; ++r)
            acc[cb][r] = (f32x16){};

    const int a_off = lw*64 + lh*16;    // co = cb*32+lw (cb via +2048), ci-half lh
    const int o0 = lh, o1 = 2 + lh;

    #pragma unroll
    for (int kh = 0; kh < 3; ++kh) {
        #pragma unroll
        for (int kw = 0; kw < 3; ++kw) {
            // ---- 12 A-loads: av[kd][cb][khalf] ----
            bf16x8 av[3][2][2];
            #pragma unroll
            for (int kd = 0; kd < 3; ++kd) {
                const char* wk = wtb + (size_t)(((kd*3 + kh)*3 + kw) << 12);
                av[kd][0][0] = *(const bf16x8*)(wk + a_off);
                av[kd][0][1] = *(const bf16x8*)(wk + 32 + a_off);
                av[kd][1][0] = *(const bf16x8*)(wk + 2048 + a_off);
                av[kd][1][1] = *(const bf16x8*)(wk + 2048 + 32 + a_off);
            }

            // ---- 12 B ds_reads: bc[j][khalf], j = slab 0..5 at ho=kh ----
            const int wp  = (wv << 5) + lw + kw - 1;
            const bool oob = ((unsigned)wp >= (unsigned)WW);
            const int wpc = oob ? lw : wp;   // zero-row uses lw so bank pattern matches
            const int sw0 = (o0 << 10) + ((wpc << 4) ^ (o0 << 4));
            const int sw1 = (o1 << 10) + ((wpc << 4) ^ (o1 << 4));
            const int zb  = oob ? 18*4096 : -1;   // per-lane select of row base

            bf16x8 bc[6][2];
            #pragma unroll
            for (int j = 0; j < 6; ++j) {
                const int rb = (j*3 + kh) << 12;
                const int base = (zb >= 0) ? zb : rb;
                bc[j][0] = *(const bf16x8*)&smem[base + sw0];
                bc[j][1] = *(const bf16x8*)&smem[base + sw1];
            }

            // ---- 48 MFMA ----
            #pragma unroll
            for (int kd = 0; kd < 3; ++kd) {
                #pragma unroll
                for (int r = 0; r < 4; ++r) {
                    const int j = r + kd;
                    acc[0][r] = __builtin_amdgcn_mfma_f32_32x32x16_bf16(av[kd][0][0], bc[j][0], acc[0][r], 0, 0, 0);
                    acc[0][r] = __builtin_amdgcn_mfma_f32_32x32x16_bf16(av[kd][0][1], bc[j][1], acc[0][r], 0, 0, 0);
                    acc[1][r] = __builtin_amdgcn_mfma_f32_32x32x16_bf16(av[kd][1][0], bc[j][0], acc[1][r], 0, 0, 0);
                    acc[1][r] = __builtin_amdgcn_mfma_f32_32x32x16_bf16(av[kd][1][1], bc[j][1], acc[1][r], 0, 0, 0);
                }
            }
        }
    }

    // epilogue: co = cb*32 + (reg&3) + 8*(reg>>2) + 4*lh ; w = wv*32+lw ; d = d0+r
    const float* ab = aggb + b*COUT;
    const int sp0 = h*WW + (wv << 5) + lw;
    #pragma unroll
    for (int cb = 0; cb < 2; ++cb) {
        #pragma unroll
        for (int reg = 0; reg < 16; ++reg) {
            const int co = (cb << 5) + (reg & 3) + ((reg >> 2) << 3) + (lh << 2);
            const float bb = ab[co];
            float* oc = out + ((size_t)(b*COUT + co))*DHW + sp0;
            #pragma unroll
            for (int r = 0; r < 4; ++r)
                oc[(size_t)(d0 + r)*HW] = acc[cb][r][reg] + bb;
        }
    }
}

// ---------------- launch ----------------
extern "C" void kernel_launch(void* const* d_in, const int* in_sizes, int n_in,
                              void* d_out, int out_size, void* d_ws, size_t ws_size,
                              hipStream_t stream) {
    const float* x           = (const float*)d_in[0];
    const float* weight      = (const float*)d_in[1];
    const float* cbias       = (const float*)d_in[2];
    const float* temperature = (const float*)d_in[3];
    const float* bn1_g       = (const float*)d_in[4];
    const float* bn1_b       = (const float*)d_in[5];
    const float* w1          = (const float*)d_in[6];
    const float* b1          = (const float*)d_in[7];
    const float* bn2_g       = (const float*)d_in[8];
    const float* bn2_b       = (const float*)d_in[9];
    const float* w2          = (const float*)d_in[10];
    const float* b2          = (const float*)d_in[11];
    const float* bn3_g       = (const float*)d_in[12];
    const float* bn3_b       = (const float*)d_in[13];
    const float* w3          = (const float*)d_in[14];
    const float* b3          = (const float*)d_in[15];
    float* out = (float*)d_out;

    char* ws = (char*)d_ws;
    float*          attn = (float*)(ws + 1024);              // 32 f
    float*          aggb = (float*)(ws + 4096);              // 512 f
    float*          pblk = (float*)(ws + 65536);             // 8*512*32 f = 512 KiB
    unsigned short* wt   = (unsigned short*)(ws + 622592);   // 884736 B
    unsigned short* xt   = (unsigned short*)(ws + 1507328);  // 64 MiB

    transpose_kernel<<<dim3(HH/4, DD, B_), 256, 0, stream>>>(x, xt, pblk);
    attn_kernel<<<1, 256, 0, stream>>>(pblk, temperature,
                                       bn1_g, bn1_b, w1, b1,
                                       bn2_g, bn2_b, w2, b2,
                                       bn3_g, bn3_b, w3, b3,
                                       cbias, attn, aggb);
    aggw_kernel<<<(B_*27*COUT*CIN)/256, 256, 0, stream>>>(weight, attn, wt);
    conv_mfma<<<dim3(64*8*8), 128, 0, stream>>>(xt, wt, aggb, out);
}

// Round 12
// 187.513 us; speedup vs baseline: 1.1382x; 1.1382x over previous
//
#include <hip/hip_runtime.h>
#include <hip/hip_bf16.h>
#include <math.h>

#define B_   8
#define CIN  32
#define COUT 64
#define KK_  4
#define DD   32
#define HH   64
#define WW   64
#define HW   (HH*WW)        // 4096
#define DHW  (DD*HH*WW)     // 131072

typedef __attribute__((ext_vector_type(8)))  short bf16x8;
typedef __attribute__((ext_vector_type(16))) float f32x16;

__device__ __forceinline__ unsigned short f2bf(float f) {
    union { float f; unsigned int u; } v; v.f = f;
    return (unsigned short)((v.u + 0x7FFFu + ((v.u >> 16) & 1u)) >> 16);   // RNE
}
__device__ __forceinline__ void gll16(const void* g, void* l) {
    __builtin_amdgcn_global_load_lds(
        (const __attribute__((address_space(1))) void*)g,
        (__attribute__((address_space(3))) void*)l, 16, 0, 0);
}

// ---------------- 1) transpose x -> bf16 xt rows + fused pooling partials ------
__global__ __launch_bounds__(256) void transpose_kernel(const float* __restrict__ x,
                                                        unsigned short* __restrict__ xt,
                                                        float* __restrict__ pblk) {
    const int t = threadIdx.x;
    const int r = t >> 6, w = t & 63;
    const int hb = blockIdx.x;
    const int h = (hb << 2) + r;
    const int d = blockIdx.y, b = blockIdx.z;

    const float* xb = x + (size_t)b*CIN*DHW + (size_t)d*HW + (size_t)h*WW + w;
    float f[CIN];
    #pragma unroll
    for (int c = 0; c < CIN; ++c) f[c] = xb[(size_t)c * DHW];

    unsigned int packed[CIN/2];
    #pragma unroll
    for (int c2 = 0; c2 < CIN/2; ++c2) {
        unsigned int lo = f2bf(f[2*c2]);
        unsigned int hi = f2bf(f[2*c2+1]);
        packed[c2] = lo | (hi << 16);
    }
    char* row = (char*)xt + (size_t)((b*DD + d)*HH + h) * 4096;
    #pragma unroll
    for (int q = 0; q < 4; ++q) {
        uint4 v = make_uint4(packed[4*q], packed[4*q+1], packed[4*q+2], packed[4*q+3]);
        *(uint4*)(row + q*1024 + (((w << 4)) ^ (q << 4))) = v;
    }

    #pragma unroll
    for (int off = 32; off > 0; off >>= 1) {
        #pragma unroll
        for (int c = 0; c < CIN; ++c) f[c] += __shfl_xor(f[c], off);
    }
    __shared__ float ws4[4][CIN];
    if ((t & 63) < CIN) ws4[r][t & 63] = f[t & 63];
    __syncthreads();
    if (t < CIN)
        pblk[(size_t)((b*DD + d)*16 + hb)*CIN + t] =
            ws4[0][t] + ws4[1][t] + ws4[2][t] + ws4[3][t];
}

// ---------------- 2) attention MLP + softmax + agg bias ----------------
__device__ __forceinline__ float gelu_erf(float v) {
    return 0.5f * v * (1.f + erff(v * 0.70710678118654752f));
}

__global__ void attn_kernel(const float* __restrict__ pblk,
                            const float* __restrict__ temperature,
                            const float* __restrict__ bn1_g, const float* __restrict__ bn1_b,
                            const float* __restrict__ w1,    const float* __restrict__ b1,
                            const float* __restrict__ bn2_g, const float* __restrict__ bn2_b,
                            const float* __restrict__ w2,    const float* __restrict__ b2,
                            const float* __restrict__ bn3_g, const float* __restrict__ bn3_b,
                            const float* __restrict__ w3,    const float* __restrict__ b3,
                            const float* __restrict__ cbias,
                            float* __restrict__ attn_out, float* __restrict__ aggb_out) {
    __shared__ float A[B_][CIN], A2[B_][CIN];
    __shared__ float L[B_][KK_], ATT[B_][KK_];
    const int t = threadIdx.x;
    const int b = t >> 5, c = t & 31;

    float pv = 0.f;
    for (int i = 0; i < DD*16; ++i) pv += pblk[(size_t)(b*DD*16 + i)*CIN + c];
    pv *= (1.f / (float)DHW);

    A[b][c] = gelu_erf(pv * bn1_g[c] + bn1_b[c]);
    __syncthreads();

    float s = b1[c];
    for (int j = 0; j < CIN; ++j) s += A[b][j] * w1[c*CIN + j];
    A2[b][c] = gelu_erf(s * bn2_g[c] + bn2_b[c]);
    __syncthreads();

    float s2 = b2[c];
    for (int j = 0; j < CIN; ++j) s2 += A2[b][j] * w2[c*CIN + j];
    s2 += pv;
    s2 = s2 * bn3_g[c] + bn3_b[c];
    __syncthreads();
    A[b][c] = s2;
    __syncthreads();

    if (c < KK_) {
        float lv = b3[c];
        for (int j = 0; j < CIN; ++j) lv += A[b][j] * w3[c*CIN + j];
        L[b][c] = lv;
    }
    __syncthreads();

    const float T = temperature[0];
    if (c < KK_) {
        float m = fmaxf(fmaxf(L[b][0], L[b][1]), fmaxf(L[b][2], L[b][3]));
        float e = expf((L[b][c] - m) / T);
        float den = 0.f;
        for (int j = 0; j < KK_; ++j) den += expf((L[b][j] - m) / T);
        float av = e / den;
        ATT[b][c] = av;
        attn_out[b*KK_ + c] = av;
    }
    __syncthreads();

    for (int o = c; o < COUT; o += CIN) {
        float sb = 0.f;
        for (int k = 0; k < KK_; ++k) sb += ATT[b][k] * cbias[k*COUT + o];
        aggb_out[b*COUT + o] = sb;
    }
}

// ---------------- 3) aggregate weights -> bf16 wt[b][kpos][co][ci] ----------------
__global__ void aggw_kernel(const float* __restrict__ weight,   // [K][O][CI][27]
                            const float* __restrict__ attn,     // [B][K]
                            unsigned short* __restrict__ wt) {  // [B][27][O][CI] bf16
    const int idx = blockIdx.x * 256 + threadIdx.x;
    const int ci   = idx & 31;
    const int co   = (idx >> 5) & 63;
    int r          = idx >> 11;
    const int kpos = r % 27;
    const int b    = r / 27;
    float s = 0.f;
    #pragma unroll
    for (int k = 0; k < KK_; ++k)
        s += attn[b*KK_ + k] * weight[((k*COUT + co)*CIN + ci)*27 + kpos];
    wt[idx] = f2bf(s);
}

// ---------------- 4) MFMA conv: ping-pong software pipeline ----------------
// flat grid 4096: id = (dt<<9)|(h<<3)|b  (b=id&7 pins b per XCD).
// block 128 = 2 waves (wv halves); wave: 64co(cb2) x 32w x 4d, 1h.
// 9 fully-unrolled (kh,kw) phases; iteration p prefetches phase p+1's
// 12 A-loads + 12 B ds_reads into the opposite register parity, then
// sched_barrier(0) + setprio-wrapped 48-MFMA burst on the current parity.
// LDS: 18 data rows + 1 zero row = 76 KiB -> 2 blocks/CU (1 wave/SIMD,
// VGPR cap 512 holds both parities: ~340 regs expected).
__global__ __launch_bounds__(128, 1) void conv_mfma(const unsigned short* __restrict__ xt,
                                                    const unsigned short* __restrict__ wt,
                                                    const float* __restrict__ aggb,
                                                    float* __restrict__ out) {
    __shared__ char smem[19 * 4096];
    const int t    = threadIdx.x;
    const int lane = t & 63;
    const int wv   = t >> 6;            // 0..1 w-half
    const int lw   = lane & 31, lh = lane >> 5;

    const int id = blockIdx.x;
    const int b  = id & 7;              // XCD-pinned
    const int h  = (id >> 3) & 63;
    const int d0 = ((id >> 9) & 7) << 2;

    const char* xb  = (const char*)xt + (size_t)(b*DD)*HH*4096;
    const char* wtb = (const char*)wt + (size_t)b * 27 * 4096;

    // zero row (idx 18): 128 threads x 2 x 16B
    *(uint4*)&smem[18*4096 + t*32]      = make_uint4(0u,0u,0u,0u);
    *(uint4*)&smem[18*4096 + t*32 + 16] = make_uint4(0u,0u,0u,0u);

    // stage 18 data rows (slab j 0..5 x ho 0..2), split across the 2 waves
    for (int rid = wv; rid < 18; rid += 2) {
        const int j = rid / 3, ho = rid % 3;
        const int zd = d0 - 1 + j, yh = h - 1 + ho;
        char* dst = smem + (size_t)(rid << 12);
        if ((unsigned)zd < DD && (unsigned)yh < HH) {
            const char* src = xb + (size_t)(zd*HH + yh)*4096 + lane*16;
            #pragma unroll
            for (int q = 0; q < 4; ++q) gll16(src + (q << 10), dst + (q << 10));
        } else {
            #pragma unroll
            for (int q = 0; q < 4; ++q)
                *(uint4*)(dst + (q << 10) + lane*16) = make_uint4(0u,0u,0u,0u);
        }
    }
    __syncthreads();

    f32x16 acc[2][4];                   // [cb][r]
    #pragma unroll
    for (int cb = 0; cb < 2; ++cb)
        #pragma unroll
        for (int r = 0; r < 4; ++r)
            acc[cb][r] = (f32x16){};

    const int a_off = lw*64 + lh*16;    // co = cb*32+lw (cb via +2048)
    const int o0 = lh, o1 = 2 + lh;

    bf16x8 av[2][12];                   // [parity][kd*4 + cb*2 + khalf]
    bf16x8 bc[2][12];                   // [parity][j*2 + khalf]

    // ---- helpers (p, par are compile-time after full unroll) ----
    auto loadA = [&](int p, int par) {
        const int kh = p / 3, kw = p % 3;
        #pragma unroll
        for (int kd = 0; kd < 3; ++kd) {
            const char* wk = wtb + (size_t)(((kd*3 + kh)*3 + kw) << 12);
            av[par][kd*4+0] = *(const bf16x8*)(wk + a_off);
            av[par][kd*4+1] = *(const bf16x8*)(wk + 32 + a_off);
            av[par][kd*4+2] = *(const bf16x8*)(wk + 2048 + a_off);
            av[par][kd*4+3] = *(const bf16x8*)(wk + 2048 + 32 + a_off);
        }
    };
    auto loadB = [&](int p, int par) {
        const int kh = p / 3, kw = p % 3;
        const int wp  = (wv << 5) + lw + kw - 1;
        const bool oob = ((unsigned)wp >= (unsigned)WW);
        const int wpc = oob ? lw : wp;         // keep bank pattern on zero row
        const int sw0 = (o0 << 10) + ((wpc << 4) ^ (o0 << 4));
        const int sw1 = (o1 << 10) + ((wpc << 4) ^ (o1 << 4));
        #pragma unroll
        for (int j = 0; j < 6; ++j) {
            const int rb = oob ? 18*4096 : ((j*3 + kh) << 12);
            bc[par][j*2+0] = *(const bf16x8*)&smem[rb + sw0];
            bc[par][j*2+1] = *(const bf16x8*)&smem[rb + sw1];
        }
    };

    loadA(0, 0);
    loadB(0, 0);

    #pragma unroll
    for (int p = 0; p < 9; ++p) {
        const int cur = p & 1, nxt = cur ^ 1;
        if (p < 8) { loadA(p + 1, nxt); loadB(p + 1, nxt); }
        __builtin_amdgcn_sched_barrier(0);   // pin: prefetch issued before burst
        __builtin_amdgcn_s_setprio(1);
        #pragma unroll
        for (int kd = 0; kd < 3; ++kd) {
            #pragma unroll
            for (int r = 0; r < 4; ++r) {
                const int j = r + kd;
                acc[0][r] = __builtin_amdgcn_mfma_f32_32x32x16_bf16(av[cur][kd*4+0], bc[cur][j*2+0], acc[0][r], 0, 0, 0);
                acc[0][r] = __builtin_amdgcn_mfma_f32_32x32x16_bf16(av[cur][kd*4+1], bc[cur][j*2+1], acc[0][r], 0, 0, 0);
                acc[1][r] = __builtin_amdgcn_mfma_f32_32x32x16_bf16(av[cur][kd*4+2], bc[cur][j*2+0], acc[1][r], 0, 0, 0);
                acc[1][r] = __builtin_amdgcn_mfma_f32_32x32x16_bf16(av[cur][kd*4+3], bc[cur][j*2+1], acc[1][r], 0, 0, 0);
            }
        }
        __builtin_amdgcn_s_setprio(0);
    }

    // epilogue: co = cb*32 + (reg&3) + 8*(reg>>2) + 4*lh ; w = wv*32+lw ; d = d0+r
    const float* ab = aggb + b*COUT;
    const int sp0 = h*WW + (wv << 5) + lw;
    #pragma unroll
    for (int cb = 0; cb < 2; ++cb) {
        #pragma unroll
        for (int reg = 0; reg < 16; ++reg) {
            const int co = (cb << 5) + (reg & 3) + ((reg >> 2) << 3) + (lh << 2);
            const float bb = ab[co];
            float* oc = out + ((size_t)(b*COUT + co))*DHW + sp0;
            #pragma unroll
            for (int r = 0; r < 4; ++r)
                oc[(size_t)(d0 + r)*HW] = acc[cb][r][reg] + bb;
        }
    }
}

// ---------------- launch ----------------
extern "C" void kernel_launch(void* const* d_in, const int* in_sizes, int n_in,
                              void* d_out, int out_size, void* d_ws, size_t ws_size,
                              hipStream_t stream) {
    const float* x           = (const float*)d_in[0];
    const float* weight      = (const float*)d_in[1];
    const float* cbias       = (const float*)d_in[2];
    const float* temperature = (const float*)d_in[3];
    const float* bn1_g       = (const float*)d_in[4];
    const float* bn1_b       = (const float*)d_in[5];
    const float* w1          = (const float*)d_in[6];
    const float* b1          = (const float*)d_in[7];
    const float* bn2_g       = (const float*)d_in[8];
    const float* bn2_b       = (const float*)d_in[9];
    const float* w2          = (const float*)d_in[10];
    const float* b2          = (const float*)d_in[11];
    const float* bn3_g       = (const float*)d_in[12];
    const float* bn3_b       = (const float*)d_in[13];
    const float* w3          = (const float*)d_in[14];
    const float* b3          = (const float*)d_in[15];
    float* out = (float*)d_out;

    char* ws = (char*)d_ws;
    float*          attn = (float*)(ws + 1024);              // 32 f
    float*          aggb = (float*)(ws + 4096);              // 512 f
    float*          pblk = (float*)(ws + 65536);             // 8*512*32 f = 512 KiB
    unsigned short* wt   = (unsigned short*)(ws + 622592);   // 884736 B
    unsigned short* xt   = (unsigned short*)(ws + 1507328);  // 64 MiB

    transpose_kernel<<<dim3(HH/4, DD, B_), 256, 0, stream>>>(x, xt, pblk);
    attn_kernel<<<1, 256, 0, stream>>>(pblk, temperature,
                                       bn1_g, bn1_b, w1, b1,
                                       bn2_g, bn2_b, w2, b2,
                                       bn3_g, bn3_b, w3, b3,
                                       cbias, attn, aggb);
    aggw_kernel<<<(B_*27*COUT*CIN)/256, 256, 0, stream>>>(weight, attn, wt);
    conv_mfma<<<dim3(64*8*8), 128, 0, stream>>>(xt, wt, aggb, out);
}